// Round 13
// baseline (127.570 us; speedup 1.0000x reference)
//
#include <hip/hip_runtime.h>
#include <hip/hip_fp16.h>
#include <math.h>

static constexpr int BLK = 256;
static constexpr int R = 8;      // queries per thread
static constexpr int TILE = 128; // scan points per LDS tile (8 B/point fp16)

__device__ __forceinline__ unsigned f2u(float f) { return __float_as_uint(f); }
__device__ __forceinline__ float u2f(unsigned u) { return __uint_as_float(u); }
__device__ __forceinline__ float lo16(unsigned u) {
    return __half2float(__ushort_as_half((unsigned short)(u & 0xFFFFu)));
}
__device__ __forceinline__ float hi16(unsigned u) {
    return __half2float(__ushort_as_half((unsigned short)(u >> 16)));
}
__device__ __forceinline__ unsigned pack16(float lo, float hi) {
    return (unsigned)__half_as_ushort(__float2half(lo)) |
           ((unsigned)__half_as_ushort(__float2half(hi)) << 16);
}

// prep: sentinels + out=0 (288 KB ws).
__global__ void prep_kernel(unsigned long long* __restrict__ o2s,
                            unsigned* __restrict__ s2o,
                            float* __restrict__ out, int N, int M) {
    int i = blockIdx.x * blockDim.x + threadIdx.x;
    if (i < N) o2s[i] = ~0ull;
    if (i < M) s2o[i] = 0xFFFFFFFFu;
    if (i == 0) out[0] = 0.0f;
}

// Fused bidirectional NN scan. Scan points stored fp16 in LDS (8 B/point ->
// 2 points per ds_read_b128, halving the LDS-pipe term R10/R11 identified as
// the binder); math stays scalar fp32 fma (the only body this compiler issues
// at full rate -- pk_fma R6/R7 and fdot2+asm R12 all regressed).
// m = w_s - s.p with s quantized to fp16 (w_s computed from quantized s, so
// d2 is exact for the quantized point; error ~1e-3/term vs threshold 47.36).
__global__ void __launch_bounds__(BLK) main_kernel(
    const float* __restrict__ P, const float* __restrict__ Ps,
    unsigned long long* __restrict__ o2s, unsigned* __restrict__ s2o,
    int N, int M, int o2sX, int o2sBlocks, int s2oX) {
    __shared__ uint4 tile4[TILE / 2];  // [x01,y01? no: per point pair records]
    int bx = blockIdx.x;

    if (bx < o2sBlocks) {
        // ---- original -> sampled: queries = P (N), scan = Ps (M), min+argmin ----
        int ix = bx % o2sX, iy = bx / o2sX;
        int ibase = ix * (BLK * R) + threadIdx.x;
        int j0 = iy * TILE;
        float px[R], py[R], pz[R], pw[R], mmin[R];
#pragma unroll
        for (int r = 0; r < R; ++r) {
            int i = ibase + r * BLK;
            float x = 0.f, y = 0.f, z = 0.f;
            if (i < N) { x = P[3 * i]; y = P[3 * i + 1]; z = P[3 * i + 2]; }
            px[r] = -x; py[r] = -y; pz[r] = -z;
            pw[r] = 0.5f * (x * x + y * y + z * z);
            mmin[r] = __builtin_inff();
        }
        if (threadIdx.x < TILE) {
            int idx = j0 + threadIdx.x;
            float x = 0.f, y = 0.f, z = 0.f, w = 60000.0f;
            if (idx < M) {
                x = (float)__float2half(Ps[3 * idx]);
                y = (float)__float2half(Ps[3 * idx + 1]);
                z = (float)__float2half(Ps[3 * idx + 2]);
                w = 0.5f * (x * x + y * y + z * z);
            }
            // point idx -> half of record (threadIdx.x>>1): [x0x1 y0y1 z0z1 w0w1]
            unsigned short hx = __half_as_ushort(__float2half(x));
            unsigned short hy = __half_as_ushort(__float2half(y));
            unsigned short hz = __half_as_ushort(__float2half(z));
            unsigned short hw = __half_as_ushort(__float2half(w));
            unsigned short* rec = (unsigned short*)&tile4[threadIdx.x >> 1];
            int h = threadIdx.x & 1;
            rec[0 + h] = hx; rec[2 + h] = hy; rec[4 + h] = hz; rec[6 + h] = hw;
        }
        __syncthreads();
#pragma unroll 4
        for (int k = 0; k < TILE / 2; ++k) {
            uint4 v = tile4[k];
            float ax = lo16(v.x), bxx = hi16(v.x);
            float ay = lo16(v.y), by = hi16(v.y);
            float az = lo16(v.z), bz = hi16(v.z);
            float aw = lo16(v.w), bw = hi16(v.w);
            unsigned iA = 2 * k, iB = 2 * k + 1;
#pragma unroll
            for (int r = 0; r < R; ++r) {
                float ma = fmaf(ax, px[r], fmaf(ay, py[r], fmaf(az, pz[r], aw)));
                float mb = fmaf(bxx, px[r], fmaf(by, py[r], fmaf(bz, pz[r], bw)));
                float pa = u2f((f2u(ma) & 0xFFFFFF00u) | iA);
                float pb = u2f((f2u(mb) & 0xFFFFFF00u) | iB);
                mmin[r] = fminf(fminf(mmin[r], pa), pb);  // -> v_min3_f32
            }
        }
#pragma unroll
        for (int r = 0; r < R; ++r) {
            int i = ibase + r * BLK;
            if (i < N) {
                unsigned j = (unsigned)j0 + (f2u(mmin[r]) & 0xFFu);
                float d2 = fmaxf(2.0f * (pw[r] + mmin[r]), 0.0f);
                atomicMin(&o2s[i], ((unsigned long long)f2u(d2) << 32) | j);
            }
        }
    } else {
        // ---- sampled -> original: queries = Ps (M), scan = P (N), min only ----
        int b = bx - o2sBlocks;
        int ix = b % s2oX, iy = b / s2oX;
        int jbase = ix * (BLK * R) + threadIdx.x;
        int i0 = iy * TILE;
        float qx[R], qy[R], qz[R], qw[R], mmin[R];
#pragma unroll
        for (int r = 0; r < R; ++r) {
            int j = jbase + r * BLK;
            float x = 0.f, y = 0.f, z = 0.f;
            if (j < M) { x = Ps[3 * j]; y = Ps[3 * j + 1]; z = Ps[3 * j + 2]; }
            qx[r] = -x; qy[r] = -y; qz[r] = -z;
            qw[r] = 0.5f * (x * x + y * y + z * z);
            mmin[r] = __builtin_inff();
        }
        if (threadIdx.x < TILE) {
            int idx = i0 + threadIdx.x;
            float x = 0.f, y = 0.f, z = 0.f, w = 60000.0f;
            if (idx < N) {
                x = (float)__float2half(P[3 * idx]);
                y = (float)__float2half(P[3 * idx + 1]);
                z = (float)__float2half(P[3 * idx + 2]);
                w = 0.5f * (x * x + y * y + z * z);
            }
            unsigned short hx = __half_as_ushort(__float2half(x));
            unsigned short hy = __half_as_ushort(__float2half(y));
            unsigned short hz = __half_as_ushort(__float2half(z));
            unsigned short hw = __half_as_ushort(__float2half(w));
            unsigned short* rec = (unsigned short*)&tile4[threadIdx.x >> 1];
            int h = threadIdx.x & 1;
            rec[0 + h] = hx; rec[2 + h] = hy; rec[4 + h] = hz; rec[6 + h] = hw;
        }
        __syncthreads();
#pragma unroll 4
        for (int k = 0; k < TILE / 2; ++k) {
            uint4 v = tile4[k];
            float ax = lo16(v.x), bxx = hi16(v.x);
            float ay = lo16(v.y), by = hi16(v.y);
            float az = lo16(v.z), bz = hi16(v.z);
            float aw = lo16(v.w), bw = hi16(v.w);
#pragma unroll
            for (int r = 0; r < R; ++r) {
                float ma = fmaf(ax, qx[r], fmaf(ay, qy[r], fmaf(az, qz[r], aw)));
                float mb = fmaf(bxx, qx[r], fmaf(by, qy[r], fmaf(bz, qz[r], bw)));
                mmin[r] = fminf(fminf(mmin[r], ma), mb);  // -> v_min3_f32
            }
        }
#pragma unroll
        for (int r = 0; r < R; ++r) {
            int j = jbase + r * BLK;
            if (j < M) {
                float d2 = fmaxf(2.0f * (qw[r] + mmin[r]), 0.0f);
                atomicMin(&s2o[j], f2u(d2));
            }
        }
    }
}

// finish: one load per query, weight, block-reduce, one atomicAdd per block.
__global__ void finish_kernel(const unsigned* __restrict__ s2o,
                              const unsigned long long* __restrict__ o2s,
                              const float* __restrict__ prob,
                              float* __restrict__ out, int N, int M) {
    int t = blockIdx.x * BLK + threadIdx.x;
    float acc = 0.0f;
    if (t < M) {
        acc = sqrtf(u2f(s2o[t])) * prob[t];
    } else if (t < M + N) {
        unsigned long long key = o2s[t - M];
        float d2 = u2f((unsigned)(key >> 32));
        unsigned jj = (unsigned)(key & 0xFFFFFFFFu);
        acc = sqrtf(d2) * prob[jj];
    }
#pragma unroll
    for (int off = 32; off > 0; off >>= 1) acc += __shfl_down(acc, off, 64);
    __shared__ float wsum[BLK / 64];
    int lane = threadIdx.x & 63, wave = threadIdx.x >> 6;
    if (lane == 0) wsum[wave] = acc;
    __syncthreads();
    if (threadIdx.x == 0) {
        float s = 0.0f;
#pragma unroll
        for (int w = 0; w < BLK / 64; ++w) s += wsum[w];
        atomicAdd(out, s);
    }
}

extern "C" void kernel_launch(void* const* d_in, const int* in_sizes, int n_in,
                              void* d_out, int out_size, void* d_ws, size_t ws_size,
                              hipStream_t stream) {
    const float* P = (const float*)d_in[0];
    const float* Ps = (const float*)d_in[1];
    const float* prob = (const float*)d_in[2];
    int N = in_sizes[0] / 3;  // 32768
    int M = in_sizes[1] / 3;  // 8192
    float* out = (float*)d_out;

    unsigned long long* o2s = (unsigned long long*)d_ws;       // N * 8 B
    unsigned* s2o = (unsigned*)((char*)d_ws + (size_t)N * 8);  // M * 4 B

    int o2sX = (N + BLK * R - 1) / (BLK * R);   // 16
    int o2sY = (M + TILE - 1) / TILE;           // 64
    int s2oX = (M + BLK * R - 1) / (BLK * R);   // 4
    int s2oY = (N + TILE - 1) / TILE;           // 256
    int o2sBlocks = o2sX * o2sY;                // 1024
    int total = o2sBlocks + s2oX * s2oY;        // 2048 = 8 blocks/CU

    prep_kernel<<<(N + BLK - 1) / BLK, BLK, 0, stream>>>(o2s, s2o, out, N, M);
    main_kernel<<<total, BLK, 0, stream>>>(P, Ps, o2s, s2o, N, M,
                                           o2sX, o2sBlocks, s2oX);
    finish_kernel<<<(N + M + BLK - 1) / BLK, BLK, 0, stream>>>(s2o, o2s, prob,
                                                               out, N, M);
}

// Round 14
// 105.976 us; speedup vs baseline: 1.2038x; 1.2038x over previous
//
#include <hip/hip_runtime.h>
#include <math.h>

static constexpr int BLK = 256;
static constexpr int R = 8;      // queries per thread
static constexpr int TILE = 128; // scan points per LDS tile (grid = 2048 blocks)
static constexpr float BIGW = 1e30f;  // finite sentinel

__device__ __forceinline__ unsigned f2u(float f) { return __float_as_uint(f); }
__device__ __forceinline__ float u2f(unsigned u) { return __uint_as_float(u); }

// prep: sentinels + out=0 (288 KB ws).
__global__ void prep_kernel(unsigned long long* __restrict__ o2s,
                            unsigned* __restrict__ s2o,
                            float* __restrict__ out, int N, int M) {
    int i = blockIdx.x * blockDim.x + threadIdx.x;
    if (i < N) o2s[i] = ~0ull;
    if (i < M) s2o[i] = 0xFFFFFFFFu;
    if (i == 0) out[0] = 0.0f;
}

// Fused bidirectional NN scan, scalar fp32 body (every packed/fp16 variant
// regressed: R6/R7/R12/R13).
// min over d2 == min over m = 0.5|scan|^2 - qry.scan ; d2 = 2*(0.5|qry|^2 + m)
// R13 post-mortem: VGPR_Count=32 < working set (8 float4 queries alone = 32)
// -> compiler parks queries in AGPRs (unified file) and shuttles via
// v_accvgpr_read each use, ~doubling the dynamic VALU stream. Fix: (a) drop
// pw[]/qw[] from the loop (recompute in epilogue from stored coords),
// (b) __launch_bounds__(256,8) caps VGPR at 64 (still 8 waves/EU max
// occupancy) and gives the allocator room for the ~42-reg working set.
__global__ void __launch_bounds__(BLK, 8) main_kernel(
    const float* __restrict__ P, const float* __restrict__ Ps,
    unsigned long long* __restrict__ o2s, unsigned* __restrict__ s2o,
    int N, int M, int o2sX, int o2sBlocks, int s2oX) {
    __shared__ float4 tile[TILE];
    int bx = blockIdx.x;

    if (bx < o2sBlocks) {
        // ---- original -> sampled: queries = P (N), scan = Ps (M), min+argmin ----
        int ix = bx % o2sX, iy = bx / o2sX;
        int ibase = ix * (BLK * R) + threadIdx.x;
        int j0 = iy * TILE;
        float px[R], py[R], pz[R], mmin[R];  // no pw in loop state
#pragma unroll
        for (int r = 0; r < R; ++r) {
            int i = ibase + r * BLK;
            float x = 0.f, y = 0.f, z = 0.f;
            if (i < N) { x = P[3 * i]; y = P[3 * i + 1]; z = P[3 * i + 2]; }
            px[r] = -x; py[r] = -y; pz[r] = -z;
            mmin[r] = __builtin_inff();
        }
        if (threadIdx.x < TILE) {
            int idx = j0 + threadIdx.x;
            float x = 0.f, y = 0.f, z = 0.f, w = BIGW;
            if (idx < M) {
                x = Ps[3 * idx]; y = Ps[3 * idx + 1]; z = Ps[3 * idx + 2];
                w = 0.5f * (x * x + y * y + z * z);
            }
            tile[threadIdx.x] = make_float4(x, y, z, w);
        }
        __syncthreads();
#pragma unroll 4
        for (int ii = 0; ii < TILE; ++ii) {
            float4 q = tile[ii];
#pragma unroll
            for (int r = 0; r < R; ++r) {
                float m = fmaf(q.x, px[r], fmaf(q.y, py[r], fmaf(q.z, pz[r], q.w)));
                float mp = u2f((f2u(m) & 0xFFFFFF00u) | (unsigned)ii);
                mmin[r] = fminf(mmin[r], mp);
            }
        }
#pragma unroll
        for (int r = 0; r < R; ++r) {
            int i = ibase + r * BLK;
            if (i < N) {
                float pw = 0.5f * (px[r] * px[r] + py[r] * py[r] + pz[r] * pz[r]);
                unsigned j = (unsigned)j0 + (f2u(mmin[r]) & 0xFFu);
                float d2 = fmaxf(2.0f * (pw + mmin[r]), 0.0f);
                atomicMin(&o2s[i], ((unsigned long long)f2u(d2) << 32) | j);
            }
        }
    } else {
        // ---- sampled -> original: queries = Ps (M), scan = P (N), min only ----
        int b = bx - o2sBlocks;
        int ix = b % s2oX, iy = b / s2oX;
        int jbase = ix * (BLK * R) + threadIdx.x;
        int i0 = iy * TILE;
        float qx[R], qy[R], qz[R], mmin[R];
#pragma unroll
        for (int r = 0; r < R; ++r) {
            int j = jbase + r * BLK;
            float x = 0.f, y = 0.f, z = 0.f;
            if (j < M) { x = Ps[3 * j]; y = Ps[3 * j + 1]; z = Ps[3 * j + 2]; }
            qx[r] = -x; qy[r] = -y; qz[r] = -z;
            mmin[r] = __builtin_inff();
        }
        if (threadIdx.x < TILE) {
            int idx = i0 + threadIdx.x;
            float x = 0.f, y = 0.f, z = 0.f, w = BIGW;
            if (idx < N) {
                x = P[3 * idx]; y = P[3 * idx + 1]; z = P[3 * idx + 2];
                w = 0.5f * (x * x + y * y + z * z);
            }
            tile[threadIdx.x] = make_float4(x, y, z, w);
        }
        __syncthreads();
#pragma unroll 4
        for (int ii = 0; ii < TILE; ++ii) {
            float4 pt = tile[ii];
#pragma unroll
            for (int r = 0; r < R; ++r) {
                float m = fmaf(pt.x, qx[r], fmaf(pt.y, qy[r], fmaf(pt.z, qz[r], pt.w)));
                mmin[r] = fminf(mmin[r], m);
            }
        }
#pragma unroll
        for (int r = 0; r < R; ++r) {
            int j = jbase + r * BLK;
            if (j < M) {
                float qw = 0.5f * (qx[r] * qx[r] + qy[r] * qy[r] + qz[r] * qz[r]);
                float d2 = fmaxf(2.0f * (qw + mmin[r]), 0.0f);
                atomicMin(&s2o[j], f2u(d2));
            }
        }
    }
}

// finish: one load per query, weight, block-reduce, one atomicAdd per block.
__global__ void finish_kernel(const unsigned* __restrict__ s2o,
                              const unsigned long long* __restrict__ o2s,
                              const float* __restrict__ prob,
                              float* __restrict__ out, int N, int M) {
    int t = blockIdx.x * BLK + threadIdx.x;
    float acc = 0.0f;
    if (t < M) {
        acc = sqrtf(u2f(s2o[t])) * prob[t];
    } else if (t < M + N) {
        unsigned long long key = o2s[t - M];
        float d2 = u2f((unsigned)(key >> 32));
        unsigned jj = (unsigned)(key & 0xFFFFFFFFu);
        acc = sqrtf(d2) * prob[jj];
    }
#pragma unroll
    for (int off = 32; off > 0; off >>= 1) acc += __shfl_down(acc, off, 64);
    __shared__ float wsum[BLK / 64];
    int lane = threadIdx.x & 63, wave = threadIdx.x >> 6;
    if (lane == 0) wsum[wave] = acc;
    __syncthreads();
    if (threadIdx.x == 0) {
        float s = 0.0f;
#pragma unroll
        for (int w = 0; w < BLK / 64; ++w) s += wsum[w];
        atomicAdd(out, s);
    }
}

extern "C" void kernel_launch(void* const* d_in, const int* in_sizes, int n_in,
                              void* d_out, int out_size, void* d_ws, size_t ws_size,
                              hipStream_t stream) {
    const float* P = (const float*)d_in[0];
    const float* Ps = (const float*)d_in[1];
    const float* prob = (const float*)d_in[2];
    int N = in_sizes[0] / 3;  // 32768
    int M = in_sizes[1] / 3;  // 8192
    float* out = (float*)d_out;

    unsigned long long* o2s = (unsigned long long*)d_ws;       // N * 8 B
    unsigned* s2o = (unsigned*)((char*)d_ws + (size_t)N * 8);  // M * 4 B

    int o2sX = (N + BLK * R - 1) / (BLK * R);   // 16
    int o2sY = (M + TILE - 1) / TILE;           // 64
    int s2oX = (M + BLK * R - 1) / (BLK * R);   // 4
    int s2oY = (N + TILE - 1) / TILE;           // 256
    int o2sBlocks = o2sX * o2sY;                // 1024
    int total = o2sBlocks + s2oX * s2oY;        // 2048 = 8 blocks/CU

    prep_kernel<<<(N + BLK - 1) / BLK, BLK, 0, stream>>>(o2s, s2o, out, N, M);
    main_kernel<<<total, BLK, 0, stream>>>(P, Ps, o2s, s2o, N, M,
                                           o2sX, o2sBlocks, s2oX);
    finish_kernel<<<(N + M + BLK - 1) / BLK, BLK, 0, stream>>>(s2o, o2s, prob,
                                                               out, N, M);
}